// Round 1
// baseline (5932.843 us; speedup 1.0000x reference)
//
#include <hip/hip_runtime.h>

#define TPB 256

// ---------------------------------------------------------------------------
// Problem constants: B=8, H=W=256, Cin=Cout=8, N=511 (=2H-1), crop offset 127
// ---------------------------------------------------------------------------

// Build DFT tables.
// Atab[k*256+n]   = exp(-2*pi*i*k*n/511)                 (forward, 511x256)
// Ctab[p*511+k]   = exp(+2*pi*i*k*(p+127)/511) / 511     (inverse+crop, 256x511)
__global__ __launch_bounds__(TPB)
void build_tables_k(float2* __restrict__ Atab, float2* __restrict__ Ctab) {
    int idx = blockIdx.x * TPB + threadIdx.x;
    const float w = (float)(6.28318530717958647692 / 511.0);
    if (idx < 511 * 256) {
        int k = idx >> 8;
        int n = idx & 255;
        int m = (k * n) % 511;
        float s, c;
        sincosf(w * (float)m, &s, &c);
        Atab[idx] = make_float2(c, -s);
    }
    if (idx < 256 * 511) {
        int p = idx / 511;
        int k = idx - p * 511;
        int m = (k * (p + 127)) % 511;
        float s, c;
        sincosf(w * (float)m, &s, &c);
        const float inv = 1.0f / 511.0f;
        Ctab[idx] = make_float2(c * inv, s * inv);
    }
}

// Transpose x from [b][n][w][i] to xT [b][i][n*256+w] for coalesced GEMM loads.
__global__ __launch_bounds__(TPB)
void transpose_x_k(const float4* __restrict__ x4, float* __restrict__ xT) {
    int idx = blockIdx.x * TPB + threadIdx.x;   // (b,n,w) flat: 8*256*256
    if (idx >= 8 * 256 * 256) return;
    float4 v0 = x4[idx * 2];
    float4 v1 = x4[idx * 2 + 1];
    float vv[8] = {v0.x, v0.y, v0.z, v0.w, v1.x, v1.y, v1.z, v1.w};
    int b  = idx >> 16;
    int nw = idx & 65535;
    float* dst = xT + ((size_t)b << 19) + nw;   // b*524288
    #pragma unroll
    for (int i = 0; i < 8; i++) dst[(size_t)i * 65536] = vv[i];
}

// ---------------------------------------------------------------------------
// Generic strided batched complex GEMM: D[m,n] = sum_k A(m,k)*B(k,n)
// AC/BC: operand is complex (float2) or real (float). DR: D real = Re(.)+bias.
// Strides are in operand elements; batch = blockIdx.z with element stride s*b.
// Tile: 64x64, BK=16, 256 threads, 4x4 micro-tile / thread.
// ---------------------------------------------------------------------------
template<bool AC, bool BC, bool DR>
__global__ __launch_bounds__(TPB)
void cgemm_k(int M, int N, int K,
             const void* __restrict__ Av, int sAm, int sAk, int sAb,
             const void* __restrict__ Bv, int sBk, int sBn, int sBb,
             void* __restrict__ Dv, int sDm, int sDn, int sDb,
             const float* __restrict__ bias)
{
    __shared__ float2 As[16][65];
    __shared__ float2 Bs[16][65];

    const int tid = threadIdx.x;
    const int tx = tid & 15, ty = tid >> 4;
    const int bm = blockIdx.y * 64, bn = blockIdx.x * 64;
    const int z = blockIdx.z;

    const float2* A2 = (const float2*)Av + (size_t)z * sAb;
    const float*  A1 = (const float*)Av  + (size_t)z * sAb;
    const float2* B2 = (const float2*)Bv + (size_t)z * sBb;
    const float*  B1 = (const float*)Bv  + (size_t)z * sBb;

    float2 acc[4][4];
    #pragma unroll
    for (int i = 0; i < 4; i++)
        #pragma unroll
        for (int j = 0; j < 4; j++) acc[i][j] = make_float2(0.f, 0.f);

    const int m0 = ty * 4, n0 = tx * 4;

    for (int k0 = 0; k0 < K; k0 += 16) {
        // A tile: 64(m) x 16(k); lanes consecutive in k (sAk==1 in all stages)
        #pragma unroll
        for (int t = 0; t < 4; t++) {
            int idx = tid + t * 256;
            int ak = idx & 15, am = idx >> 4;
            int gm = bm + am, gk = k0 + ak;
            float2 val = make_float2(0.f, 0.f);
            if (gm < M && gk < K) {
                if constexpr (AC) val = A2[(size_t)gm * sAm + (size_t)gk * sAk];
                else              val.x = A1[(size_t)gm * sAm + (size_t)gk * sAk];
            }
            As[ak][am] = val;
        }
        // B tile: 16(k) x 64(n); lanes consecutive in n
        #pragma unroll
        for (int t = 0; t < 4; t++) {
            int idx = tid + t * 256;
            int bni = idx & 63, bki = idx >> 6;
            int gk = k0 + bki, gn = bn + bni;
            float2 val = make_float2(0.f, 0.f);
            if (gk < K && gn < N) {
                if constexpr (BC) val = B2[(size_t)gk * sBk + (size_t)gn * sBn];
                else              val.x = B1[(size_t)gk * sBk + (size_t)gn * sBn];
            }
            Bs[bki][bni] = val;
        }
        __syncthreads();

        #pragma unroll
        for (int kk = 0; kk < 16; kk++) {
            float2 a[4], b[4];
            #pragma unroll
            for (int i = 0; i < 4; i++) a[i] = As[kk][m0 + i];
            #pragma unroll
            for (int j = 0; j < 4; j++) b[j] = Bs[kk][n0 + j];
            #pragma unroll
            for (int i = 0; i < 4; i++)
                #pragma unroll
                for (int j = 0; j < 4; j++) {
                    if constexpr (AC && BC) {
                        acc[i][j].x += a[i].x * b[j].x - a[i].y * b[j].y;
                        if constexpr (!DR)
                            acc[i][j].y += a[i].x * b[j].y + a[i].y * b[j].x;
                    } else if constexpr (AC && !BC) {
                        acc[i][j].x += a[i].x * b[j].x;
                        acc[i][j].y += a[i].y * b[j].x;
                    } else {
                        acc[i][j].x += a[i].x * b[j].x;
                    }
                }
        }
        __syncthreads();
    }

    float bz = 0.f;
    if (DR && bias != nullptr) bz = bias[z];

    #pragma unroll
    for (int i = 0; i < 4; i++) {
        int gm = bm + m0 + i;
        if (gm >= M) continue;
        #pragma unroll
        for (int j = 0; j < 4; j++) {
            int gn = bn + n0 + j;
            if (gn >= N) continue;
            size_t off = (size_t)gm * sDm + (size_t)gn * sDn + (size_t)z * sDb;
            if constexpr (DR) ((float*)Dv)[off] = acc[i][j].x + bz;
            else              ((float2*)Dv)[off] = acc[i][j];
        }
    }
}

// ---------------------------------------------------------------------------
// Pointwise spectrum einsum for one batch image:
//   yfT[o][pt] = sum_i F2[i][pt] * (Kr[pt,i,o] + i*Ki[pt,i,o]),  pt = k1*511+k2
// F2 layout [i][pt] (i-plane), kernel layout [pt*64 + i*8 + o].
// ---------------------------------------------------------------------------
__global__ __launch_bounds__(TPB)
void einsum_k(const float2* __restrict__ F2, const float* __restrict__ Kr,
              const float* __restrict__ Ki, float2* __restrict__ yfT)
{
    int pt = blockIdx.x * TPB + threadIdx.x;
    if (pt >= 511 * 511) return;

    float xr[8], xi[8];
    #pragma unroll
    for (int i = 0; i < 8; i++) {
        float2 v = F2[(size_t)i * 261121 + pt];
        xr[i] = v.x; xi[i] = v.y;
    }

    float ar[8], ai[8];
    #pragma unroll
    for (int o = 0; o < 8; o++) { ar[o] = 0.f; ai[o] = 0.f; }

    size_t base = (size_t)pt * 64;
    #pragma unroll
    for (int i = 0; i < 8; i++) {
        float krv[8], kiv[8];
        const float4* kr4 = (const float4*)(Kr + base + i * 8);
        const float4* ki4 = (const float4*)(Ki + base + i * 8);
        ((float4*)krv)[0] = kr4[0]; ((float4*)krv)[1] = kr4[1];
        ((float4*)kiv)[0] = ki4[0]; ((float4*)kiv)[1] = ki4[1];
        #pragma unroll
        for (int o = 0; o < 8; o++) {
            ar[o] += xr[i] * krv[o] - xi[i] * kiv[o];
            ai[o] += xr[i] * kiv[o] + xi[i] * krv[o];
        }
    }
    #pragma unroll
    for (int o = 0; o < 8; o++)
        yfT[(size_t)o * 261121 + pt] = make_float2(ar[o], ai[o]);
}

// ---------------------------------------------------------------------------

extern "C" void kernel_launch(void* const* d_in, const int* in_sizes, int n_in,
                              void* d_out, int out_size, void* d_ws, size_t ws_size,
                              hipStream_t stream) {
    const float* x    = (const float*)d_in[0];     // (8,256,256,8)
    const float* Kr   = (const float*)d_in[1];     // (2,511,511,8,8): real plane
    const float* Ki   = Kr + 16711744;             // imag plane
    const float* bias = (const float*)d_in[2];     // (8,)
    float* out = (float*)d_out;                    // (8,256,256,8)
    char* ws = (char*)d_ws;

    // Workspace layout (bytes), total ~60.7 MB:
    float2* Atab = (float2*)(ws + 0);          //  1,046,528  (511*256 c64)
    float2* Ctab = (float2*)(ws + 1046528);    //  1,046,528  (256*511 c64)
    float*  xT   = (float*) (ws + 2093056);    // 16,777,216  (8*8*65536 f32)
    float2* F1   = (float2*)(ws + 18870272);   //  8,372,224  (8*511*256 c64) = G1
    float2* F2   = (float2*)(ws + 27242496);   // 16,711,744  (8*261121 c64)
    float2* yfT  = (float2*)(ws + 43954240);   // 16,711,744  (8*261121 c64)

    build_tables_k<<<511, TPB, 0, stream>>>(Atab, Ctab);
    transpose_x_k<<<2048, TPB, 0, stream>>>((const float4*)x, xT);

    for (int b = 0; b < 8; b++) {
        // S1: F1[i][k1][w] = sum_n A[k1,n] * xT[b,i,n,w]   (cplx * real)
        cgemm_k<true, false, false><<<dim3(4, 8, 8), TPB, 0, stream>>>(
            511, 256, 256,
            Atab, 256, 1, 0,
            xT + (size_t)b * 524288, 256, 1, 65536,
            F1, 256, 1, 130816, nullptr);

        // S2: F2[i][k1*511+k2] = sum_w F1[i][k1][w] * A[k2,w]
        cgemm_k<true, true, false><<<dim3(8, 8, 8), TPB, 0, stream>>>(
            511, 511, 256,
            F1, 256, 1, 130816,
            Atab, 1, 256, 0,
            F2, 511, 1, 261121, nullptr);

        // S3: per-frequency 8x8 complex channel mix, write yfT[o][pt]
        einsum_k<<<1021, TPB, 0, stream>>>(F2, Kr, Ki, yfT);

        // S4: G1[o][p][k2] = sum_k1 C[p,k1] * yfT[o][k1*511+k2]
        cgemm_k<true, true, false><<<dim3(8, 4, 8), TPB, 0, stream>>>(
            256, 511, 511,
            Ctab, 511, 1, 0,
            yfT, 511, 1, 261121,
            F1, 511, 1, 130816, nullptr);

        // S5: out[b][p][q][o] = Re( sum_k2 G1[o][p][k2] * C[q,k2] ) + bias[o]
        cgemm_k<true, true, true><<<dim3(4, 4, 8), TPB, 0, stream>>>(
            256, 256, 511,
            F1, 511, 1, 130816,
            Ctab, 1, 511, 0,
            out + (size_t)b * 524288, 2048, 8, 1, bias);
    }
}

// Round 2
// 1937.011 us; speedup vs baseline: 3.0629x; 3.0629x over previous
//
#include <hip/hip_runtime.h>

#define TPB 256

typedef float v2f __attribute__((ext_vector_type(2)));

__device__ __forceinline__ v2f fma2(v2f a, v2f b, v2f c) {
    return __builtin_elementwise_fma(a, b, c);
}

// ---------------------------------------------------------------------------
// Problem constants: B=8, H=W=256, Cin=Cout=8, N=511 (=2H-1), crop offset 127
// ---------------------------------------------------------------------------

// DFT tables.
// Atab [k*256+n] = exp(-2*pi*i*k*n/511)              (forward, 511x256)
// AtabT[n*511+k] = same, transposed                  (256x511)
// Ctab [p*511+k] = exp(+2*pi*i*k*(p+127)/511)/511    (inverse+crop, 256x511)
// CtabT[k*256+p] = same, transposed                  (511x256)
__global__ __launch_bounds__(TPB)
void build_tables_k(float2* __restrict__ Atab, float2* __restrict__ AtabT,
                    float2* __restrict__ Ctab, float2* __restrict__ CtabT) {
    int idx = blockIdx.x * TPB + threadIdx.x;
    const float w = (float)(6.28318530717958647692 / 511.0);
    if (idx < 511 * 256) {
        int k = idx >> 8;
        int n = idx & 255;
        int m = (k * n) % 511;
        float s, c;
        sincosf(w * (float)m, &s, &c);
        float2 v = make_float2(c, -s);
        Atab[idx] = v;
        AtabT[n * 511 + k] = v;
    }
    if (idx < 256 * 511) {
        int p = idx / 511;
        int k = idx - p * 511;
        int m = (k * (p + 127)) % 511;
        float s, c;
        sincosf(w * (float)m, &s, &c);
        const float inv = 1.0f / 511.0f;
        float2 v = make_float2(c * inv, s * inv);
        Ctab[idx] = v;
        CtabT[k * 256 + p] = v;
    }
}

// Transpose x from [b][n][w][i] to xT [(b*8+i)][n*256+w] for coalesced GEMM loads.
__global__ __launch_bounds__(TPB)
void transpose_x_k(const float4* __restrict__ x4, float* __restrict__ xT) {
    int idx = blockIdx.x * TPB + threadIdx.x;   // (b,n,w) flat: 8*256*256
    if (idx >= 8 * 256 * 256) return;
    float4 v0 = x4[idx * 2];
    float4 v1 = x4[idx * 2 + 1];
    float vv[8] = {v0.x, v0.y, v0.z, v0.w, v1.x, v1.y, v1.z, v1.w};
    int b  = idx >> 16;
    int nw = idx & 65535;
    float* dst = xT + ((size_t)b << 19) + nw;   // b*8*65536
    #pragma unroll
    for (int i = 0; i < 8; i++) dst[(size_t)i * 65536] = vv[i];
}

// ---------------------------------------------------------------------------
// Strided batched complex GEMM: D[m,n] = sum_k A(m,k)*B(k,n)
// A always complex. BC: B complex. DR: D = Re(.) + bias[z&7].
// sAk == 1 and sBn == 1 required (coalesced staging).
// z (blockIdx.z) batch: A += z*sAb, B += z*sBb, D += (z>>3)*sDzHi + (z&7)*sDzLo.
// Tile 64x64, BK=16, 256 threads, 4x4 complex micro-tile, SoA LDS + pk-fma.
// ---------------------------------------------------------------------------
template<bool BC, bool DR>
__global__ __launch_bounds__(TPB)
void cgemm_k(int M, int N, int K,
             const float2* __restrict__ A2, int sAm, int sAb,
             const float2* __restrict__ B2, int sBk, int sBb,
             float* __restrict__ Dv, int sDm, int sDn, int sDzHi, int sDzLo,
             const float* __restrict__ bias)
{
    __shared__ float Asr[16][68];
    __shared__ float Asi[16][68];
    __shared__ float Bsr[16][68];
    __shared__ float Bsi[16][68];

    const int tid = threadIdx.x;
    const int tx = tid & 15, ty = tid >> 4;
    const int bm = blockIdx.y * 64, bn = blockIdx.x * 64;
    const int z = blockIdx.z;

    const float2* A = A2 + (size_t)z * sAb;
    const float2* B = B2 + (size_t)z * sBb;

    v2f acc[4][4];
    #pragma unroll
    for (int i = 0; i < 4; i++)
        #pragma unroll
        for (int j = 0; j < 4; j++) acc[i][j] = (v2f){0.f, 0.f};

    const int m0 = ty * 4, n0 = tx * 4;

    for (int k0 = 0; k0 < K; k0 += 16) {
        // A tile: 64(m) x 16(k); lanes consecutive in k (sAk==1)
        #pragma unroll
        for (int t = 0; t < 4; t++) {
            int idx = tid + t * 256;
            int ak = idx & 15, am = idx >> 4;
            int gm = bm + am, gk = k0 + ak;
            float2 val = make_float2(0.f, 0.f);
            if (gm < M && gk < K) val = A[(size_t)gm * sAm + gk];
            Asr[ak][am] = val.x;
            Asi[ak][am] = val.y;
        }
        // B tile: 16(k) x 64(n); lanes consecutive in n (sBn==1)
        #pragma unroll
        for (int t = 0; t < 4; t++) {
            int idx = tid + t * 256;
            int bni = idx & 63, bki = idx >> 6;
            int gk = k0 + bki, gn = bn + bni;
            if constexpr (BC) {
                float2 val = make_float2(0.f, 0.f);
                if (gk < K && gn < N) val = B[(size_t)gk * sBk + gn];
                Bsr[bki][bni] = val.x;
                Bsi[bki][bni] = val.y;
            } else {
                float val = 0.f;
                if (gk < K && gn < N) val = ((const float*)B)[(size_t)gk * sBk + gn];
                Bsr[bki][bni] = val;
            }
        }
        __syncthreads();

        #pragma unroll
        for (int kk = 0; kk < 16; kk++) {
            float ar4[4], ai4[4], br4[4], bi4[4];
            *(float4*)ar4 = *(const float4*)&Asr[kk][m0];
            *(float4*)ai4 = *(const float4*)&Asi[kk][m0];
            *(float4*)br4 = *(const float4*)&Bsr[kk][n0];
            if constexpr (BC) *(float4*)bi4 = *(const float4*)&Bsi[kk][n0];

            if constexpr (BC && !DR) {
                v2f bv[4], bs[4];
                #pragma unroll
                for (int j = 0; j < 4; j++) {
                    bv[j] = (v2f){br4[j], bi4[j]};
                    bs[j] = (v2f){-bi4[j], br4[j]};
                }
                #pragma unroll
                for (int i = 0; i < 4; i++) {
                    v2f arr = (v2f){ar4[i], ar4[i]};
                    v2f aii = (v2f){ai4[i], ai4[i]};
                    #pragma unroll
                    for (int j = 0; j < 4; j++) {
                        acc[i][j] = fma2(arr, bv[j], acc[i][j]);
                        acc[i][j] = fma2(aii, bs[j], acc[i][j]);
                    }
                }
            } else if constexpr (BC && DR) {
                // real part only: ar*br - ai*bi
                #pragma unroll
                for (int i = 0; i < 4; i++)
                    #pragma unroll
                    for (int j = 0; j < 4; j++) {
                        acc[i][j].x = fmaf(ar4[i], br4[j], acc[i][j].x);
                        acc[i][j].x = fmaf(-ai4[i], bi4[j], acc[i][j].x);
                    }
            } else {
                // B real: (ar+i*ai)*br
                #pragma unroll
                for (int i = 0; i < 4; i++) {
                    v2f av = (v2f){ar4[i], ai4[i]};
                    #pragma unroll
                    for (int j = 0; j < 4; j++) {
                        v2f bb = (v2f){br4[j], br4[j]};
                        acc[i][j] = fma2(av, bb, acc[i][j]);
                    }
                }
            }
        }
        __syncthreads();
    }

    float bz = 0.f;
    if constexpr (DR) { if (bias != nullptr) bz = bias[z & 7]; }

    size_t dbase = (size_t)(z >> 3) * sDzHi + (size_t)(z & 7) * sDzLo;
    #pragma unroll
    for (int i = 0; i < 4; i++) {
        int gm = bm + m0 + i;
        if (gm >= M) continue;
        #pragma unroll
        for (int j = 0; j < 4; j++) {
            int gn = bn + n0 + j;
            if (gn >= N) continue;
            size_t off = dbase + (size_t)gm * sDm + (size_t)gn * sDn;
            if constexpr (DR) Dv[off] = acc[i][j].x + bz;
            else ((float2*)Dv)[off] = make_float2(acc[i][j].x, acc[i][j].y);
        }
    }
}

// ---------------------------------------------------------------------------
// Pointwise spectrum einsum, IN PLACE on F2, one image per blockIdx.y:
//   F2[img][o][pt] = sum_i F2[img][i][pt] * (Kr[pt,i,o] + i*Ki[pt,i,o])
// ---------------------------------------------------------------------------
__global__ __launch_bounds__(TPB)
void einsum_k(float2* __restrict__ F2, const float* __restrict__ Kr,
              const float* __restrict__ Ki)
{
    int pt = blockIdx.x * TPB + threadIdx.x;
    if (pt >= 511 * 511) return;
    float2* F = F2 + (size_t)blockIdx.y * (8 * 261121);

    float xr[8], xi[8];
    #pragma unroll
    for (int i = 0; i < 8; i++) {
        float2 v = F[(size_t)i * 261121 + pt];
        xr[i] = v.x; xi[i] = v.y;
    }

    float ar[8], ai[8];
    #pragma unroll
    for (int o = 0; o < 8; o++) { ar[o] = 0.f; ai[o] = 0.f; }

    size_t base = (size_t)pt * 64;
    #pragma unroll
    for (int i = 0; i < 8; i++) {
        float krv[8], kiv[8];
        const float4* kr4 = (const float4*)(Kr + base + i * 8);
        const float4* ki4 = (const float4*)(Ki + base + i * 8);
        ((float4*)krv)[0] = kr4[0]; ((float4*)krv)[1] = kr4[1];
        ((float4*)kiv)[0] = ki4[0]; ((float4*)kiv)[1] = ki4[1];
        #pragma unroll
        for (int o = 0; o < 8; o++) {
            ar[o] = fmaf(xr[i], krv[o], ar[o]);
            ar[o] = fmaf(-xi[i], kiv[o], ar[o]);
            ai[o] = fmaf(xr[i], kiv[o], ai[o]);
            ai[o] = fmaf(xi[i], krv[o], ai[o]);
        }
    }
    #pragma unroll
    for (int o = 0; o < 8; o++)
        F[(size_t)o * 261121 + pt] = make_float2(ar[o], ai[o]);
}

// ---------------------------------------------------------------------------

extern "C" void kernel_launch(void* const* d_in, const int* in_sizes, int n_in,
                              void* d_out, int out_size, void* d_ws, size_t ws_size,
                              hipStream_t stream) {
    const float* x    = (const float*)d_in[0];     // (8,256,256,8)
    const float* Kr   = (const float*)d_in[1];     // (2,511,511,8,8): real plane
    const float* Ki   = Kr + 16711744;             // imag plane
    const float* bias = (const float*)d_in[2];     // (8,)
    float* out = (float*)d_out;                    // (8,256,256,8)
    char* ws = (char*)d_ws;

    // Fixed workspace: 4 tables (4x 1,046,528 B) + xT (16,777,216 B)
    float2* Atab  = (float2*)(ws + 0);
    float2* AtabT = (float2*)(ws + 1046528);
    float2* Ctab  = (float2*)(ws + 2093056);
    float2* CtabT = (float2*)(ws + 3139584);
    float*  xT    = (float*) (ws + 4186112);
    const size_t fixedEnd = 4186112 + 16777216;    // 20,963,328

    // Per-pass buffers for g images: F1 g*8,372,224 B; F2 g*16,711,744 B.
    int g = 1;
    for (int cand = 8; cand >= 1; cand >>= 1) {
        if (fixedEnd + (size_t)cand * (8372224 + 16711744) <= ws_size) { g = cand; break; }
    }
    float2* F1 = (float2*)(ws + fixedEnd);
    float2* F2 = (float2*)(ws + fixedEnd + (size_t)g * 8372224);

    build_tables_k<<<511, TPB, 0, stream>>>(Atab, AtabT, Ctab, CtabT);
    transpose_x_k<<<2048, TPB, 0, stream>>>((const float4*)x, xT);

    for (int b0 = 0; b0 < 8; b0 += g) {
        int Z = g * 8;
        // S1: F1[z][k1*256+w] = sum_n Atab[k1,n] * xT[b0*8+z][n*256+w]  (B real)
        cgemm_k<false, false><<<dim3(4, 8, Z), TPB, 0, stream>>>(
            511, 256, 256,
            Atab, 256, 0,
            (const float2*)(xT + (size_t)b0 * 8 * 65536), 256, 65536 / 2, // sBb in f32 elems: pass as float2*... see note
            (float*)F1, 256, 1, 130816 * 8, 130816, nullptr);

        // S2: F2[z][k1*511+k2] = sum_w F1[z][k1*256+w] * AtabT[w*511+k2]
        cgemm_k<true, false><<<dim3(8, 8, Z), TPB, 0, stream>>>(
            511, 511, 256,
            F1, 256, 130816,
            AtabT, 511, 0,
            (float*)F2, 511, 1, 261121 * 8, 261121, nullptr);

        // S3: in-place 8x8 complex channel mix per frequency point
        einsum_k<<<dim3(1021, g), TPB, 0, stream>>>(F2, Kr, Ki);

        // S4: F1[z][p*511+k2] = sum_k1 Ctab[p*511+k1] * F2[z][k1*511+k2]
        cgemm_k<true, false><<<dim3(8, 4, Z), TPB, 0, stream>>>(
            256, 511, 511,
            Ctab, 511, 0,
            F2, 511, 261121,
            (float*)F1, 511, 1, 130816 * 8, 130816, nullptr);

        // S5: out[b0+img][p][q][o] = Re(sum_k2 F1[z][p*511+k2]*CtabT[k2*256+q]) + bias[o]
        cgemm_k<true, true><<<dim3(4, 4, Z), TPB, 0, stream>>>(
            256, 256, 511,
            F1, 511, 130816,
            CtabT, 256, 0,
            out + (size_t)b0 * 524288, 2048, 8, 524288, 1, bias);
    }
}

// Round 4
// 975.058 us; speedup vs baseline: 6.0846x; 1.9866x over previous
//
#include <hip/hip_runtime.h>

#define TPB 256

// ---------------------------------------------------------------------------
// B=8, H=W=256, Cin=Cout=8, N=511 (=2H-1), crop offset 127.
// Half-spectrum (k2 in [0,256)) via Hermitian-symmetrized kernel Ke.
// All GEMM dims padded to 512/256 (zero rows via zeroed table entries).
// ---------------------------------------------------------------------------

// Atab [k*256+n]  = exp(-2*pi*i*k*n/511), k in [0,512), row 511 = 0
// AtabTh[w*256+k2]= exp(-2*pi*i*k2*w/511), k2 in [0,256)
// Ctab [p*512+k1] = exp(+2*pi*i*k1*(p+127)/511)/511, k1 in [0,512), col 511 = 0
// Ct2T [k2*256+q] = w(k2)*exp(+2*pi*i*k2*(q+127)/511)/511, w(0)=1 else 2
__global__ __launch_bounds__(TPB)
void build_tables_k(float2* __restrict__ Atab, float2* __restrict__ AtabTh,
                    float2* __restrict__ Ctab, float2* __restrict__ Ct2T) {
    int idx = blockIdx.x * TPB + threadIdx.x;   // [0, 131072)
    const float w = (float)(6.28318530717958647692 / 511.0);
    {
        int k = idx >> 8, n = idx & 255;
        float2 v = make_float2(0.f, 0.f);
        if (k < 511) {
            int m = (k * n) % 511;
            float s, c; sincosf(w * (float)m, &s, &c);
            v = make_float2(c, -s);
        }
        Atab[idx] = v;
        if (k < 256) AtabTh[n * 256 + k] = v;
    }
    {
        int p = idx >> 9, k1 = idx & 511;
        float2 v = make_float2(0.f, 0.f);
        if (k1 < 511) {
            int m = (k1 * (p + 127)) % 511;
            float s, c; sincosf(w * (float)m, &s, &c);
            v = make_float2(c / 511.f, s / 511.f);
        }
        Ctab[p * 512 + k1] = v;
    }
    if (idx < 65536) {
        int k2 = idx >> 8, q = idx & 255;
        int m = (k2 * (q + 127)) % 511;
        float s, c; sincosf(w * (float)m, &s, &c);
        float sc = (k2 == 0 ? 1.f : 2.f) / 511.f;
        Ct2T[idx] = make_float2(c * sc, s * sc);
    }
}

// x [b][n][w][i] -> xT [(b*8+i)][n*256+w]
__global__ __launch_bounds__(TPB)
void transpose_x_k(const float4* __restrict__ x4, float* __restrict__ xT) {
    int idx = blockIdx.x * TPB + threadIdx.x;   // 8*256*256
    if (idx >= 8 * 256 * 256) return;
    float4 v0 = x4[idx * 2];
    float4 v1 = x4[idx * 2 + 1];
    float vv[8] = {v0.x, v0.y, v0.z, v0.w, v1.x, v1.y, v1.z, v1.w};
    int b  = idx >> 16;
    int nw = idx & 65535;
    float* dst = xT + ((size_t)b << 19) + nw;
    #pragma unroll
    for (int i = 0; i < 8; i++) dst[(size_t)i * 65536] = vv[i];
}

// Hermitian-symmetrize kernel into transposed half-table planes:
//   KeR/KeI[io][k1*256+k2] for k1 in [0,511), k2 in [0,256)
//   Ke(k) = 0.5*(Kc(k) + conj(Kc(-k)))
__global__ __launch_bounds__(TPB)
void ksym_k(const float* __restrict__ Kr, const float* __restrict__ Ki,
            float* __restrict__ KeR, float* __restrict__ KeI) {
    __shared__ float LR[64][65];
    __shared__ float LI[64][65];
    const int tid = threadIdx.x;
    const int pt0 = blockIdx.x * 64;            // 2044 blocks * 64 = 130816
    #pragma unroll
    for (int t = 0; t < 4; t++) {
        int idx = tid + t * 256;
        int ptl = idx >> 4, j = idx & 15;
        int pt2 = pt0 + ptl;
        int k1 = pt2 >> 8, k2 = pt2 & 255;
        int k1m = (511 - k1) % 511;
        int k2m = (511 - k2) % 511;
        size_t so = ((size_t)(k1  * 511 + k2 )) * 64 + j * 4;
        size_t mo = ((size_t)(k1m * 511 + k2m)) * 64 + j * 4;
        float4 rs = *(const float4*)(Kr + so);
        float4 rm = *(const float4*)(Kr + mo);
        float4 is = *(const float4*)(Ki + so);
        float4 im = *(const float4*)(Ki + mo);
        LR[j * 4 + 0][ptl] = 0.5f * (rs.x + rm.x);
        LR[j * 4 + 1][ptl] = 0.5f * (rs.y + rm.y);
        LR[j * 4 + 2][ptl] = 0.5f * (rs.z + rm.z);
        LR[j * 4 + 3][ptl] = 0.5f * (rs.w + rm.w);
        LI[j * 4 + 0][ptl] = 0.5f * (is.x - im.x);
        LI[j * 4 + 1][ptl] = 0.5f * (is.y - im.y);
        LI[j * 4 + 2][ptl] = 0.5f * (is.z - im.z);
        LI[j * 4 + 3][ptl] = 0.5f * (is.w - im.w);
    }
    __syncthreads();
    #pragma unroll
    for (int t = 0; t < 32; t++) {
        int idx = tid + t * 256;
        int plane = idx >> 6, ptl = idx & 63;
        if (plane < 64) KeR[(size_t)plane * 131072 + pt0 + ptl] = LR[plane][ptl];
        else KeI[(size_t)(plane - 64) * 131072 + pt0 + ptl] = LI[plane - 64][ptl];
    }
}

// ---------------------------------------------------------------------------
// Batched complex GEMM, no bounds checks (M,N mult of 64; K mult of 16).
// A complex (z-stride sAb float2). BC: B complex. DR: D=Re(.)+bias[z&7].
// Asi stored NEGATED in LDS; negations in math via free VOP3 neg modifiers.
// Tile 64x64, BK=16, 256 threads, 4x4 micro-tile.
// ---------------------------------------------------------------------------
template<bool BC, bool DR>
__global__ __launch_bounds__(TPB)
void cgemm_k(int K,
             const float2* __restrict__ A2, int sAm, int sAb,
             const float2* __restrict__ B2, int sBk, int sBb,
             float* __restrict__ Dv, int sDm, int sDn, int sDzHi, int sDzLo,
             const float* __restrict__ bias)
{
    __shared__ float Asr[16][68];
    __shared__ float Asi[16][68];
    __shared__ float Bsr[16][68];
    __shared__ float Bsi[16][68];

    const int tid = threadIdx.x;
    const int tx = tid & 15, ty = tid >> 4;
    const int bm = blockIdx.y * 64, bn = blockIdx.x * 64;
    const int z = blockIdx.z;

    const float2* A = A2 + (size_t)z * sAb;
    const float2* B = B2 + (size_t)z * sBb;

    const int ak  = tid & 15, am0 = tid >> 4;   // A-stage: row am0+16t, col ak
    const int bni = tid & 63, bk0 = tid >> 6;   // B-stage: row bk0+4t, col bni

    const float2* aP[4];
    const float2* bP[4];
    const float*  bPf[4];
    #pragma unroll
    for (int t = 0; t < 4; t++) {
        aP[t] = A + (size_t)(bm + am0 + 16 * t) * sAm + ak;
        if constexpr (BC) bP[t]  = B + (size_t)(bk0 + 4 * t) * sBk + bn + bni;
        else              bPf[t] = (const float*)B + (size_t)(bk0 + 4 * t) * sBk + bn + bni;
    }

    float accR[4][4] = {{0.f}}, accI[4][4] = {{0.f}};
    const int m0 = ty * 4, n0 = tx * 4;

    for (int k0 = 0; k0 < K; k0 += 16) {
        #pragma unroll
        for (int t = 0; t < 4; t++) {
            float2 v = *aP[t]; aP[t] += 16;
            Asr[ak][am0 + 16 * t] = v.x;
            Asi[ak][am0 + 16 * t] = -v.y;       // negated imag
        }
        #pragma unroll
        for (int t = 0; t < 4; t++) {
            if constexpr (BC) {
                float2 v = *bP[t]; bP[t] += (size_t)16 * sBk;
                Bsr[bk0 + 4 * t][bni] = v.x;
                Bsi[bk0 + 4 * t][bni] = v.y;
            } else {
                float v = *bPf[t]; bPf[t] += (size_t)16 * sBk;
                Bsr[bk0 + 4 * t][bni] = v;
            }
        }
        __syncthreads();

        #pragma unroll
        for (int kk = 0; kk < 16; kk++) {
            float ar4[4], an4[4], br4[4], bi4[4];
            *(float4*)ar4 = *(const float4*)&Asr[kk][m0];
            *(float4*)an4 = *(const float4*)&Asi[kk][m0];   // = -ai
            *(float4*)br4 = *(const float4*)&Bsr[kk][n0];
            if constexpr (BC) *(float4*)bi4 = *(const float4*)&Bsi[kk][n0];
            #pragma unroll
            for (int i = 0; i < 4; i++)
                #pragma unroll
                for (int j = 0; j < 4; j++) {
                    if constexpr (BC && !DR) {
                        accR[i][j] = fmaf(ar4[i], br4[j], accR[i][j]);
                        accR[i][j] = fmaf(an4[i], bi4[j], accR[i][j]);
                        accI[i][j] = fmaf(ar4[i], bi4[j], accI[i][j]);
                        accI[i][j] = fmaf(-an4[i], br4[j], accI[i][j]);
                    } else if constexpr (BC && DR) {
                        accR[i][j] = fmaf(ar4[i], br4[j], accR[i][j]);
                        accR[i][j] = fmaf(an4[i], bi4[j], accR[i][j]);
                    } else {
                        accR[i][j] = fmaf(ar4[i], br4[j], accR[i][j]);
                        accI[i][j] = fmaf(-an4[i], br4[j], accI[i][j]);
                    }
                }
        }
        __syncthreads();
    }

    float bz = 0.f;
    if constexpr (DR) { if (bias != nullptr) bz = bias[z & 7]; }

    const size_t dbase = (size_t)(z >> 3) * sDzHi + (size_t)(z & 7) * sDzLo;
    #pragma unroll
    for (int i = 0; i < 4; i++) {
        int gm = bm + m0 + i;
        #pragma unroll
        for (int j = 0; j < 4; j++) {
            int gn = bn + n0 + j;
            size_t off = dbase + (size_t)gm * sDm + (size_t)gn * sDn;
            if constexpr (DR) Dv[off] = accR[i][j] + bz;
            else ((float2*)Dv)[off] = make_float2(accR[i][j], accI[i][j]);
        }
    }
}

// ---------------------------------------------------------------------------
// In-place channel mix on half-spectrum, one (pt, image) per thread:
//   F2[m*8+o][pt] = sum_i F2[m*8+i][pt] * Ke[i*8+o][pt]
// ---------------------------------------------------------------------------
__global__ __launch_bounds__(TPB)
void einsum_k(float2* __restrict__ F2, const float* __restrict__ KeR,
              const float* __restrict__ KeI)
{
    int pt = blockIdx.x * TPB + threadIdx.x;    // [0, 131072)
    float2* F = F2 + (size_t)blockIdx.y * (8 * 131072);

    float xr[8], xi[8];
    #pragma unroll
    for (int i = 0; i < 8; i++) {
        float2 v = F[(size_t)i * 131072 + pt];
        xr[i] = v.x; xi[i] = v.y;
    }
    float ar[8] = {0.f}, ai[8] = {0.f};
    #pragma unroll
    for (int i = 0; i < 8; i++) {
        #pragma unroll
        for (int o = 0; o < 8; o++) {
            float kr = KeR[(size_t)(i * 8 + o) * 131072 + pt];
            float ki = KeI[(size_t)(i * 8 + o) * 131072 + pt];
            ar[o] = fmaf(xr[i], kr, ar[o]);
            ar[o] = fmaf(-xi[i], ki, ar[o]);
            ai[o] = fmaf(xr[i], ki, ai[o]);
            ai[o] = fmaf(xi[i], kr, ai[o]);
        }
    }
    #pragma unroll
    for (int o = 0; o < 8; o++)
        F[(size_t)o * 131072 + pt] = make_float2(ar[o], ai[o]);
}

// ---------------------------------------------------------------------------

extern "C" void kernel_launch(void* const* d_in, const int* in_sizes, int n_in,
                              void* d_out, int out_size, void* d_ws, size_t ws_size,
                              hipStream_t stream) {
    const float* x    = (const float*)d_in[0];
    const float* Kr   = (const float*)d_in[1];
    const float* Ki   = Kr + 16711744;          // 511*511*64
    const float* bias = (const float*)d_in[2];
    float* out = (float*)d_out;
    char* ws = (char*)d_ws;

    float2* Atab   = (float2*)(ws + 0);          //  1,048,576
    float2* AtabTh = (float2*)(ws + 1048576);    //    524,288
    float2* Ctab   = (float2*)(ws + 1572864);    //  1,048,576
    float2* Ct2T   = (float2*)(ws + 2621440);    //    524,288
    float*  xT     = (float*) (ws + 3145728);    // 16,777,216
    float*  KeR    = (float*) (ws + 19922944);   // 33,554,432
    float*  KeI    = (float*) (ws + 53477376);   // 33,554,432
    const size_t fixedEnd = 87031808;

    int g = 1;
    for (int cand = 8; cand >= 1; cand >>= 1) {
        if (fixedEnd + (size_t)cand * 16777216 <= ws_size) { g = cand; break; }
    }
    float2* F1 = (float2*)(ws + fixedEnd);                        // g*8,388,608
    float2* F2 = (float2*)(ws + fixedEnd + (size_t)g * 8388608);  // g*8,388,608

    build_tables_k<<<512, TPB, 0, stream>>>(Atab, AtabTh, Ctab, Ct2T);
    transpose_x_k<<<2048, TPB, 0, stream>>>((const float4*)x, xT);
    ksym_k<<<2044, TPB, 0, stream>>>(Kr, Ki, KeR, KeI);

    for (int b0 = 0; b0 < 8; b0 += g) {
        int Z = g * 8;
        // S1: F1[z][k1*256+w] = sum_n Atab[k1,n]*x[z][n][w]   (B real)
        cgemm_k<false, false><<<dim3(4, 8, Z), TPB, 0, stream>>>(
            256, Atab, 256, 0,
            (const float2*)xT + (size_t)b0 * 8 * 32768, 256, 32768,
            (float*)F1, 256, 1, 1048576, 131072, nullptr);

        // S2: F2[z][k1*256+k2] = sum_w F1[z][k1*256+w]*AtabTh[w*256+k2]
        cgemm_k<true, false><<<dim3(4, 8, Z), TPB, 0, stream>>>(
            256, F1, 256, 131072,
            AtabTh, 256, 0,
            (float*)F2, 256, 1, 1048576, 131072, nullptr);

        // S3: in-place channel mix
        einsum_k<<<dim3(512, g), TPB, 0, stream>>>(F2, KeR, KeI);

        // S4: F1[z][p*256+k2] = sum_k1 Ctab[p*512+k1]*F2[z][k1*256+k2]
        cgemm_k<true, false><<<dim3(4, 4, Z), TPB, 0, stream>>>(
            512, Ctab, 512, 0,
            F2, 256, 131072,
            (float*)F1, 256, 1, 1048576, 131072, nullptr);

        // S5: out[m][p][q][o] = Re(sum_k2 F1[z][p*256+k2]*Ct2T[k2*256+q]) + bias[o]
        cgemm_k<true, true><<<dim3(4, 4, Z), TPB, 0, stream>>>(
            256, F1, 256, 131072,
            Ct2T, 256, 0,
            out + (size_t)b0 * 524288, 2048, 8, 524288, 1, bias);
    }
}